// Round 14
// baseline (128.953 us; speedup 1.0000x reference)
//
#include <hip/hip_runtime.h>

// SSIM loss, fused separable Gaussian (11x11, sigma=1.5) over [32,3,512,512] f32.
// R14 = R12/R13 structure, ASM-FREE (the "s"-constraint on derived pointers
// cannot be satisfied -- backend computes 64b pointer math on VALU and won't
// readfirstlane for inline asm; R8 evidence shows sched_barrier(0) alone DOES
// batch plain loads: 28 dests live across the fence -> VGPR-forced batch).
//  - persistent slab blocks: 1536 (96 img x 2 halves x 8 slabs) = 6/CU exact;
//    each runs 16 vertical 4x256 tiles.
//  - 14-row register window slides by 4 rows/tile: 8 plain loads issued at
//    tile top (pinned by sched_barrier), consumed only at loop-bottom slide
//    -> compiler's auto-vmcnt sits AFTER the FIR+H compute = T14 overlap.
//  - loads per output row 3.5 -> 1.16; border masks only slabs 0/7 (uniform).
//  - per-block plain store ws[b] + tiny reduce kernel (R11 atomic fix).
// Kept: XCD-bijective swizzle, pk f32x2 dual-chain FIR, linear stats LDS.

typedef float f32x2 __attribute__((ext_vector_type(2)));

#define IH 512
#define IW 512
#define TH 4                 // output rows per tile
#define TW 256               // output cols per tile
#define PW 266               // TW + 10 FIR cols
#define LPW 268              // stats row stride in f32x2
#define KT 16                // tiles per block (vertical)
#define NSLAB 8              // 128 ht-tiles / KT
#define NBLK 1536            // 96 * 2 * NSLAB
#define CPX 192              // NBLK / 8 XCDs (exact -> bijective swizzle)
#define NPIX 25165824.0f     // 96*512*512
#define NTHR 320

constexpr float GW[11] = {
    0.00102838f, 0.00759877f, 0.03600078f, 0.10936070f, 0.21300554f,
    0.26601173f,
    0.21300554f, 0.10936070f, 0.03600078f, 0.00759877f, 0.00102838f
};
constexpr float C1f = 0.0001f;  // 0.01^2
constexpr float C2f = 0.0009f;  // 0.03^2

__global__ __launch_bounds__(256) void ssim_reduce(
    const float* __restrict__ ws, float* __restrict__ out)
{
    __shared__ float wsum[4];
    const int tid = threadIdx.x;
    float s = 0.0f;
    #pragma unroll
    for (int i = 0; i < 6; ++i) s += ws[tid + i * 256];
    #pragma unroll
    for (int off = 32; off > 0; off >>= 1) s += __shfl_down(s, off, 64);
    if ((tid & 63) == 0) wsum[tid >> 6] = s;
    __syncthreads();
    if (tid == 0) {
        out[0] = 1.0f - (wsum[0] + wsum[1] + wsum[2] + wsum[3]) * (1.0f / NPIX);
    }
}

__device__ __forceinline__ int hclamp(int h) {
    return h < 0 ? 0 : (h > IH - 1 ? IH - 1 : h);
}

__global__ __launch_bounds__(NTHR, 2) void ssim_main(
    const float* __restrict__ pred,
    const float* __restrict__ targ,
    float* __restrict__ ws)
{
    __shared__ __align__(16) f32x2 lds01[TH][LPW];   // (E[p], E[t])
    __shared__ __align__(16) f32x2 lds23[TH][LPW];   // (E[p^2+t^2], E[p*t])
    __shared__ float wsum[5];

    const int tid = threadIdx.x;

    // -------- XCD swizzle: one XCD covers whole column strips --------------
    const int b  = blockIdx.x;
    const int tl = (b & 7) * CPX + (b >> 3);
    const int slab = tl & (NSLAB - 1);       // slabs of a strip contiguous
    const int wt   = (tl >> 3) & 1;
    const int bc   = tl >> 4;
    const int j0   = slab * KT;              // first ht tile

    const float* __restrict__ P = pred + (size_t)bc * (IH * IW);
    const float* __restrict__ T = targ + (size_t)bc * (IH * IW);

    // per-thread column; clamped -> ALL lanes load safely
    const int w = wt * TW - 5 + tid;
    const float wm = ((unsigned)w < (unsigned)IW) ? 1.0f : 0.0f;
    const int wc = w < 0 ? 0 : (w > IW - 1 ? IW - 1 : w);
    const bool active = tid < PW;
    const bool border = (slab == 0) || (slab == NSLAB - 1);

    // -------- prologue: fill 14-row register window ------------------------
    float pv[14], tv[14];
    float nlp[4], nlt[4];
    #pragma unroll
    for (int rr = 0; rr < 14; ++rr) {
        const int hc = hclamp(4 * j0 - 5 + rr);         // uniform
        pv[rr] = P[(size_t)hc * IW + wc];
        tv[rr] = T[(size_t)hc * IW + wc];
    }
    __builtin_amdgcn_sched_barrier(0);   // all 28 issued before any use

    float lsum = 0.0f;
    const f32x2 wmv = {wm, wm};

    for (int jj = 0; jj < KT; ++jj) {
        const int j = j0 + jj;

        // ---- issue next tile's 4 new rows; pinned here by fences ----------
        if (jj < KT - 1) {
            #pragma unroll
            for (int i = 0; i < 4; ++i) {
                const int hc = hclamp(4 * j + 9 + i);   // uniform
                nlp[i] = P[(size_t)hc * IW + wc];
                nlt[i] = T[(size_t)hc * IW + wc];
            }
        }
        __builtin_amdgcn_sched_barrier(0);   // loads can't sink past here

        // ---- V-phase: dual-chain packed FIR from register window ----------
        {
            f32x2 a01[TH], a23[TH];
            #pragma unroll
            for (int ro = 0; ro < TH; ++ro) {
                a01[ro].x = 0.f; a01[ro].y = 0.f;
                a23[ro].x = 0.f; a23[ro].y = 0.f;
            }
            #pragma unroll
            for (int rr = 0; rr < 14; ++rr) {
                float p = pv[rr], t = tv[rr];
                if (border) {                 // uniform branch
                    const int row = 4 * j - 5 + rr;
                    const float rmk = ((unsigned)row < (unsigned)IH) ? 1.0f : 0.0f;
                    p *= rmk; t *= rmk;
                }
                f32x2 s01; s01.x = p; s01.y = t;
                f32x2 s23;
                s23.x = fmaf(p, p, t * t);
                s23.y = p * t;
                #pragma unroll
                for (int ro = 0; ro < TH; ++ro) {
                    const int k = rr - ro;       // static after unroll
                    if (k >= 0 && k < 11) {
                        const f32x2 g = {GW[k], GW[k]};
                        a01[ro] = __builtin_elementwise_fma(g, s01, a01[ro]);
                        a23[ro] = __builtin_elementwise_fma(g, s23, a23[ro]);
                    }
                }
            }
            if (active) {
                #pragma unroll
                for (int ro = 0; ro < TH; ++ro) {
                    lds01[ro][tid] = a01[ro] * wmv;
                    lds23[ro][tid] = a23[ro] * wmv;
                }
            }
        }
        __syncthreads();

        // ---- H-phase: horizontal conv + SSIM epilogue ---------------------
        if (tid < 256) {
            const int r  = tid >> 6;            // 0..3
            const int c0 = (tid & 63) << 2;     // 0..252

            float4 u4[7], v4[7];
            const float4* b01 = reinterpret_cast<const float4*>(&lds01[r][c0]);
            const float4* b23 = reinterpret_cast<const float4*>(&lds23[r][c0]);
            #pragma unroll
            for (int q = 0; q < 7; ++q) { u4[q] = b01[q]; v4[q] = b23[q]; }
            const f32x2* x01 = reinterpret_cast<const f32x2*>(u4);   // 14
            const f32x2* x23 = reinterpret_cast<const f32x2*>(v4);

            #pragma unroll
            for (int jo = 0; jo < 4; ++jo) {
                f32x2 acc01; acc01.x = 0.f; acc01.y = 0.f;
                f32x2 acc23; acc23.x = 0.f; acc23.y = 0.f;
                #pragma unroll
                for (int k = 0; k < 11; ++k) {
                    const f32x2 g = {GW[k], GW[k]};
                    acc01 = __builtin_elementwise_fma(g, x01[jo + k], acc01);
                    acc23 = __builtin_elementwise_fma(g, x23[jo + k], acc23);
                }
                const float m1  = acc01.x;
                const float m2  = acc01.y;
                const float sPP = acc23.x;      // E[p^2]+E[t^2]
                const float e12 = acc23.y;      // E[p*t]
                const float m1m2 = m1 * m2;
                const float msq  = fmaf(m1, m1, m2 * m2);
                const float num = fmaf(2.0f, m1m2, C1f) * fmaf(2.0f, (e12 - m1m2), C2f);
                const float den = (msq + C1f) * ((sPP - msq) + C2f);
                lsum = fmaf(num, __builtin_amdgcn_rcpf(den), lsum);
            }
        }
        __syncthreads();   // stats LDS reusable next tile

        // ---- slide window: auto-vmcnt waits HERE (after FIR+H compute) ----
        if (jj < KT - 1) {
            #pragma unroll
            for (int i = 0; i < 10; ++i) { pv[i] = pv[i + 4]; tv[i] = tv[i + 4]; }
            #pragma unroll
            for (int i = 0; i < 4; ++i)  { pv[10 + i] = nlp[i]; tv[10 + i] = nlt[i]; }
        }
    }

    // ---------------- Reduction: wave shuffle -> LDS -> plain store --------
    #pragma unroll
    for (int off = 32; off > 0; off >>= 1) lsum += __shfl_down(lsum, off, 64);
    const int lane = tid & 63;
    const int wv   = tid >> 6;              // 0..4
    if (lane == 0) wsum[wv] = lsum;
    __syncthreads();
    if (tid == 0) {
        ws[b] = wsum[0] + wsum[1] + wsum[2] + wsum[3] + wsum[4];
    }
}

extern "C" void kernel_launch(void* const* d_in, const int* in_sizes, int n_in,
                              void* d_out, int out_size, void* d_ws, size_t ws_size,
                              hipStream_t stream) {
    const float* pred = (const float*)d_in[0];
    const float* targ = (const float*)d_in[1];
    float* out = (float*)d_out;
    float* wsf = (float*)d_ws;               // needs 1536 floats

    hipLaunchKernelGGL(ssim_main, dim3(NBLK), dim3(NTHR), 0, stream,
                       pred, targ, wsf);
    hipLaunchKernelGGL(ssim_reduce, dim3(1), dim3(256), 0, stream, wsf, out);
}